// Round 1
// baseline (320.658 us; speedup 1.0000x reference)
//
#include <hip/hip_runtime.h>
#include <hip/hip_bf16.h>

#define BB 4
#define TT 4096
#define DM 1024
#define HH 64
#define RTOT (BB * TT)  // 16384

typedef __attribute__((ext_vector_type(4))) float f32x4;
typedef __attribute__((ext_vector_type(8))) short s16x8;

__device__ __forceinline__ ushort f2bf_bits(float f) {
    union { float f; unsigned u; } x;
    x.f = f;
    unsigned r = x.u + 0x7FFFu + ((x.u >> 16) & 1u);  // RNE to bf16
    return (ushort)(r >> 16);
}

// ---- transpose + convert W: wt[m][h][d] = W_m[d][h] as bf16 bits ----
__global__ __launch_bounds__(256) void k_wtrans(const float* __restrict__ wq,
                                                const float* __restrict__ wk,
                                                const float* __restrict__ wv,
                                                ushort* __restrict__ wt) {
    int idx = blockIdx.x * 256 + threadIdx.x;  // 0 .. 3*65536-1
    int m = idx >> 16, rem = idx & 65535;
    int h = rem >> 10, d = rem & 1023;
    const float* W = (m == 0) ? wq : (m == 1) ? wk : wv;
    wt[idx] = f2bf_bits(W[d * HH + h]);
}

// ---- projections: qh/kh row-major bf16, v transposed -> vt[h][row] ----
__global__ __launch_bounds__(256) void k_proj(const float* __restrict__ q,
                                              const float* __restrict__ k,
                                              const float* __restrict__ v,
                                              const ushort* __restrict__ wt,
                                              ushort* __restrict__ qh,
                                              ushort* __restrict__ kh,
                                              ushort* __restrict__ vt) {
    int bid = blockIdx.x;        // 0..767
    int mat = bid >> 8;          // 0:q 1:k 2:v
    int rt  = bid & 255;         // row tile (64 rows)
    const float* src = (mat == 0) ? q : (mat == 1) ? k : v;
    const ushort* w = wt + mat * (HH * DM);

    int tid = threadIdx.x;
    int wv_ = tid >> 6, l = tid & 63, lr = l & 15, lg = l >> 4;
    int rbase = rt * 64 + wv_ * 16;

    f32x4 acc[4] = {};

    for (int ks = 0; ks < 32; ++ks) {
        int k0 = ks * 32;
        const float* ap = src + (size_t)(rbase + lr) * DM + k0 + lg * 8;
        float4 a0 = *reinterpret_cast<const float4*>(ap);
        float4 a1 = *reinterpret_cast<const float4*>(ap + 4);
        s16x8 af;
        af[0] = f2bf_bits(a0.x); af[1] = f2bf_bits(a0.y);
        af[2] = f2bf_bits(a0.z); af[3] = f2bf_bits(a0.w);
        af[4] = f2bf_bits(a1.x); af[5] = f2bf_bits(a1.y);
        af[6] = f2bf_bits(a1.z); af[7] = f2bf_bits(a1.w);
#pragma unroll
        for (int f = 0; f < 4; ++f) {
            s16x8 bf_ = *reinterpret_cast<const s16x8*>(w + (lr + 16 * f) * DM + k0 + lg * 8);
            acc[f] = __builtin_amdgcn_mfma_f32_16x16x32_bf16(af, bf_, acc[f], 0, 0, 0);
        }
    }

#pragma unroll
    for (int f = 0; f < 4; ++f)
#pragma unroll
        for (int r = 0; r < 4; ++r) {
            int row = rbase + lg * 4 + r;   // C/D: row=(l>>4)*4+reg
            int col = lr + 16 * f;          //      col=l&15 (+16 per frag)
            ushort bv = f2bf_bits(acc[f][r]);
            if (mat == 0)      qh[row * HH + col] = bv;
            else if (mat == 1) kh[row * HH + col] = bv;
            else               vt[(size_t)col * RTOT + row] = bv;
        }
}

// ---- fused causal flash attention ----
__global__ __launch_bounds__(256) void k_attn(const ushort* __restrict__ qh,
                                              const ushort* __restrict__ kh,
                                              const ushort* __restrict__ vt,
                                              float* __restrict__ out) {
    __shared__ ushort plds[4][1024];  // per-wave private 16x64 bf16, XOR-swizzled

    int b = blockIdx.x >> 6, qt = blockIdx.x & 63;
    int tid = threadIdx.x, wv_ = tid >> 6, l = tid & 63, lr = l & 15, lg = l >> 4;
    int qrow0 = b * TT + qt * 64 + wv_ * 16;  // global q-row base for this wave

    // hoist Q fragments (A-layout: row=l&15, k=(l>>4)*8+j)
    s16x8 qf[2];
#pragma unroll
    for (int s = 0; s < 2; ++s)
        qf[s] = *reinterpret_cast<const s16x8*>(qh + (size_t)(qrow0 + lr) * HH + s * 32 + lg * 8);

    f32x4 oacc[4] = {};
    float mrow[4] = {-INFINITY, -INFINITY, -INFINITY, -INFINITY};
    float ssum[4] = {};
    const float KS = 0.1803368801111204f;  // log2(e)/8 : folds the 1/sqrt(64) scale

    ushort* pw = &plds[wv_][0];

    for (int kt = 0; kt <= qt; ++kt) {
        int kb = b * TT + kt * 64;  // global kv row base

        // QK^T: scores S[q=(lg*4+reg)][kv=lr+16f]
        f32x4 sacc[4] = {};
#pragma unroll
        for (int s = 0; s < 2; ++s)
#pragma unroll
            for (int f = 0; f < 4; ++f) {
                s16x8 kf = *reinterpret_cast<const s16x8*>(
                    kh + (size_t)(kb + 16 * f + lr) * HH + s * 32 + lg * 8);
                sacc[f] = __builtin_amdgcn_mfma_f32_16x16x32_bf16(qf[s], kf, sacc[f], 0, 0, 0);
            }

        if (kt == qt) {  // diagonal tile: causal mask
#pragma unroll
            for (int f = 0; f < 4; ++f)
#pragma unroll
                for (int r = 0; r < 4; ++r)
                    if (16 * f + lr > wv_ * 16 + lg * 4 + r) sacc[f][r] = -1e30f;
        }

        // online softmax per q-row (row's 16 kv cols live in one 16-lane group)
        float pv[4][4];
#pragma unroll
        for (int r = 0; r < 4; ++r) {
            float tm = fmaxf(fmaxf(sacc[0][r], sacc[1][r]), fmaxf(sacc[2][r], sacc[3][r]));
            tm = fmaxf(tm, __shfl_xor(tm, 1));
            tm = fmaxf(tm, __shfl_xor(tm, 2));
            tm = fmaxf(tm, __shfl_xor(tm, 4));
            tm = fmaxf(tm, __shfl_xor(tm, 8));
            float nm = fmaxf(mrow[r], tm);
            float corr = exp2f((mrow[r] - nm) * KS);
            mrow[r] = nm;
            float ts = 0.f;
#pragma unroll
            for (int f = 0; f < 4; ++f) {
                float p = exp2f((sacc[f][r] - nm) * KS);
                pv[f][r] = p;
                ts += p;
            }
            ts += __shfl_xor(ts, 1);
            ts += __shfl_xor(ts, 2);
            ts += __shfl_xor(ts, 4);
            ts += __shfl_xor(ts, 8);
            ssum[r] = ssum[r] * corr + ts;
#pragma unroll
            for (int f = 0; f < 4; ++f) oacc[f][r] *= corr;
        }

        // P -> LDS bf16, XOR-swizzled (kills 128B-stride bank conflict)
#pragma unroll
        for (int f = 0; f < 4; ++f)
#pragma unroll
            for (int r = 0; r < 4; ++r) {
                int qr = lg * 4 + r;
                int boff = (qr * 128 + (16 * f + lr) * 2) ^ ((qr & 7) << 4);
                *reinterpret_cast<ushort*>(reinterpret_cast<char*>(pw) + boff) =
                    f2bf_bits(pv[f][r]);
            }

        // read P back as A-fragments (wave-private region: no barrier needed)
        s16x8 pf[2];
#pragma unroll
        for (int s = 0; s < 2; ++s) {
            int boff = (lr * 128 + (s * 32 + lg * 8) * 2) ^ ((lr & 7) << 4);
            pf[s] = *reinterpret_cast<const s16x8*>(reinterpret_cast<const char*>(pw) + boff);
        }

        // PV: out[q][h] += P[q][kv] * V[kv][h]; B-frag contiguous via vt[h][row]
#pragma unroll
        for (int s = 0; s < 2; ++s)
#pragma unroll
            for (int f = 0; f < 4; ++f) {
                s16x8 vf = *reinterpret_cast<const s16x8*>(
                    vt + (size_t)(16 * f + lr) * RTOT + kb + s * 32 + lg * 8);
                oacc[f] = __builtin_amdgcn_mfma_f32_16x16x32_bf16(pf[s], vf, oacc[f], 0, 0, 0);
            }
    }

#pragma unroll
    for (int r = 0; r < 4; ++r) {
        float inv = 1.0f / ssum[r];
#pragma unroll
        for (int f = 0; f < 4; ++f)
            out[(size_t)(qrow0 + lg * 4 + r) * HH + 16 * f + lr] = oacc[f][r] * inv;
    }
}

extern "C" void kernel_launch(void* const* d_in, const int* in_sizes, int n_in,
                              void* d_out, int out_size, void* d_ws, size_t ws_size,
                              hipStream_t stream) {
    const float* q  = (const float*)d_in[0];
    const float* k  = (const float*)d_in[1];
    const float* v  = (const float*)d_in[2];
    const float* wq = (const float*)d_in[3];
    const float* wk = (const float*)d_in[4];
    const float* wv = (const float*)d_in[5];
    // d_in[6] = mask: deterministic causal, not needed
    float* out = (float*)d_out;

    char* ws = (char*)d_ws;
    ushort* qh = (ushort*)(ws);                 // 2 MB  [16384][64] bf16
    ushort* kh = (ushort*)(ws + (2u << 20));    // 2 MB  [16384][64] bf16
    ushort* vt = (ushort*)(ws + (4u << 20));    // 2 MB  [64][16384] bf16 (transposed)
    ushort* wt = (ushort*)(ws + (6u << 20));    // 384 KB [3][64][1024] bf16

    k_wtrans<<<768, 256, 0, stream>>>(wq, wk, wv, wt);
    k_proj<<<768, 256, 0, stream>>>(q, k, v, wt, qh, kh, vt);
    k_attn<<<256, 256, 0, stream>>>(qh, kh, vt, out);
}

// Round 2
// 227.974 us; speedup vs baseline: 1.4066x; 1.4066x over previous
//
#include <hip/hip_runtime.h>
#include <hip/hip_bf16.h>

#define BB 4
#define TT 4096
#define DM 1024
#define HH 64
#define RTOT (BB * TT)  // 16384
#define SLOTS_PER_B 544 // sum_{qt=0..63} ceil((qt+1)/4)

typedef __attribute__((ext_vector_type(4))) float f32x4;
typedef __attribute__((ext_vector_type(8))) short s16x8;

__device__ __forceinline__ ushort f2bf_bits(float f) {
    union { float f; unsigned u; } x;
    x.f = f;
    unsigned r = x.u + 0x7FFFu + ((x.u >> 16) & 1u);  // RNE to bf16
    return (ushort)(r >> 16);
}

// ---- transpose + convert W: wt[m][h][d] = W_m[d][h] as bf16 bits ----
__global__ __launch_bounds__(256) void k_wtrans(const float* __restrict__ wq,
                                                const float* __restrict__ wk,
                                                const float* __restrict__ wv,
                                                ushort* __restrict__ wt) {
    int idx = blockIdx.x * 256 + threadIdx.x;  // 0 .. 3*65536-1
    int m = idx >> 16, rem = idx & 65535;
    int h = rem >> 10, d = rem & 1023;
    const float* W = (m == 0) ? wq : (m == 1) ? wk : wv;
    wt[idx] = f2bf_bits(W[d * HH + h]);
}

// ---- projections: qh/kh row-major bf16, v transposed -> vt[h][row] ----
__global__ __launch_bounds__(256) void k_proj(const float* __restrict__ q,
                                              const float* __restrict__ k,
                                              const float* __restrict__ v,
                                              const ushort* __restrict__ wt,
                                              ushort* __restrict__ qh,
                                              ushort* __restrict__ kh,
                                              ushort* __restrict__ vt) {
    int bid = blockIdx.x;        // 0..767
    int mat = bid >> 8;          // 0:q 1:k 2:v
    int rt  = bid & 255;         // row tile (64 rows)
    const float* src = (mat == 0) ? q : (mat == 1) ? k : v;
    const ushort* w = wt + mat * (HH * DM);

    int tid = threadIdx.x;
    int wid = tid >> 6, l = tid & 63, lr = l & 15, lg = l >> 4;
    int rbase = rt * 64 + wid * 16;

    f32x4 acc[4] = {};

    const float* ap = src + (size_t)(rbase + lr) * DM + lg * 8;
    // 2-deep register prefetch of the fp32 A stream (HBM latency ~900cy)
    float4 a0 = *reinterpret_cast<const float4*>(ap);
    float4 a1 = *reinterpret_cast<const float4*>(ap + 4);

    for (int ks = 0; ks < 32; ++ks) {
        float4 n0, n1;
        if (ks < 31) {
            n0 = *reinterpret_cast<const float4*>(ap + (ks + 1) * 32);
            n1 = *reinterpret_cast<const float4*>(ap + (ks + 1) * 32 + 4);
        }
        int k0 = ks * 32;
        s16x8 af;
        af[0] = f2bf_bits(a0.x); af[1] = f2bf_bits(a0.y);
        af[2] = f2bf_bits(a0.z); af[3] = f2bf_bits(a0.w);
        af[4] = f2bf_bits(a1.x); af[5] = f2bf_bits(a1.y);
        af[6] = f2bf_bits(a1.z); af[7] = f2bf_bits(a1.w);
#pragma unroll
        for (int f = 0; f < 4; ++f) {
            s16x8 bf_ = *reinterpret_cast<const s16x8*>(w + (lr + 16 * f) * DM + k0 + lg * 8);
            acc[f] = __builtin_amdgcn_mfma_f32_16x16x32_bf16(af, bf_, acc[f], 0, 0, 0);
        }
        a0 = n0; a1 = n1;
    }

#pragma unroll
    for (int f = 0; f < 4; ++f)
#pragma unroll
        for (int r = 0; r < 4; ++r) {
            int row = rbase + lg * 4 + r;   // C/D: row=(l>>4)*4+reg
            int col = lr + 16 * f;          //      col=l&15 (+16 per frag)
            ushort bv = f2bf_bits(acc[f][r]);
            if (mat == 0)      qh[row * HH + col] = bv;
            else if (mat == 1) kh[row * HH + col] = bv;
            else               vt[(size_t)col * RTOT + row] = bv;
        }
}

// ---- split-KV partial attention: one (b, 64-row qtile, 256-col chunk) per block ----
__global__ __launch_bounds__(256) void k_attn_part(const ushort* __restrict__ qh,
                                                   const ushort* __restrict__ kh,
                                                   const ushort* __restrict__ vt,
                                                   float* __restrict__ pm,
                                                   float* __restrict__ pl,
                                                   float* __restrict__ pO) {
    int c = blockIdx.x, qt = blockIdx.y, b = blockIdx.z;
    int M4 = qt >> 2, rem = qt & 3;
    int nch = M4 + 1;
    if (c >= nch) return;
    int slot = b * SLOTS_PER_B + 2 * M4 * (M4 + 1) + rem * (M4 + 1) + c;

    __shared__ ushort plds[4][4096];  // per-wave 16x256 bf16 P tile, XOR-swizzled

    int tid = threadIdx.x, wid = tid >> 6, l = tid & 63, lr = l & 15, lg = l >> 4;
    int qrow_l = qt * 64 + wid * 16;               // local (within batch)
    size_t qrow_g = (size_t)b * TT + qrow_l;
    int kb_l = c * 256;
    size_t kb_g = (size_t)b * TT + kb_l;
    const float KS = 0.1803368801111204f;          // log2(e)/8

    // Q fragments (A-layout: row=l&15, k=(l>>4)*8+j)
    s16x8 qf[2];
#pragma unroll
    for (int s = 0; s < 2; ++s)
        qf[s] = *reinterpret_cast<const s16x8*>(qh + (qrow_g + lr) * HH + s * 32 + lg * 8);

    // QK^T over the full 256-col chunk: S[q=(lg*4+r)][kv=16f+lr]
    f32x4 sacc[16] = {};
#pragma unroll
    for (int s = 0; s < 2; ++s)
#pragma unroll
        for (int f = 0; f < 16; ++f) {
            s16x8 kf = *reinterpret_cast<const s16x8*>(
                kh + (kb_g + 16 * f + lr) * HH + s * 32 + lg * 8);
            sacc[f] = __builtin_amdgcn_mfma_f32_16x16x32_bf16(qf[s], kf, sacc[f], 0, 0, 0);
        }

    // causal mask — only the last chunk can contain the diagonal
    if (c == nch - 1) {
#pragma unroll
        for (int f = 0; f < 16; ++f)
#pragma unroll
            for (int r = 0; r < 4; ++r)
                if (kb_l + 16 * f + lr > qrow_l + lg * 4 + r) sacc[f][r] = -1e30f;
    }

    // plain softmax within chunk (no online rescale); one 16-lane reduce per row
    ushort* pw = &plds[wid][0];
#pragma unroll
    for (int r = 0; r < 4; ++r) {
        float tm = -1e30f;
#pragma unroll
        for (int f = 0; f < 16; ++f) tm = fmaxf(tm, sacc[f][r]);
        tm = fmaxf(tm, __shfl_xor(tm, 1));
        tm = fmaxf(tm, __shfl_xor(tm, 2));
        tm = fmaxf(tm, __shfl_xor(tm, 4));
        tm = fmaxf(tm, __shfl_xor(tm, 8));
        float ts = 0.f;
#pragma unroll
        for (int f = 0; f < 16; ++f) {
            float p = exp2f((sacc[f][r] - tm) * KS);
            sacc[f][r] = p;
            ts += p;
        }
        ts += __shfl_xor(ts, 1);
        ts += __shfl_xor(ts, 2);
        ts += __shfl_xor(ts, 4);
        ts += __shfl_xor(ts, 8);
        int rit = wid * 16 + lg * 4 + r;
        if (lr == 0) {
            pm[(size_t)slot * 64 + rit] = tm;
            pl[(size_t)slot * 64 + rit] = ts;
        }
    }

    // P -> LDS bf16 (XOR-swizzle kills the 512B-stride bank conflict)
#pragma unroll
    for (int f = 0; f < 16; ++f)
#pragma unroll
        for (int r = 0; r < 4; ++r) {
            int qr = lg * 4 + r;
            int boff = (qr * 512 + (16 * f + lr) * 2) ^ ((qr & 7) << 4);
            *reinterpret_cast<ushort*>(reinterpret_cast<char*>(pw) + boff) =
                f2bf_bits(sacc[f][r]);
        }

    // PV over the 4 kv-tiles of the chunk (wave-private LDS: no barrier)
    f32x4 oacc[4] = {};
#pragma unroll
    for (int tt = 0; tt < 4; ++tt) {
        s16x8 pf[2];
#pragma unroll
        for (int s = 0; s < 2; ++s) {
            int boff = (lr * 512 + (tt * 64 + s * 32 + lg * 8) * 2) ^ ((lr & 7) << 4);
            pf[s] = *reinterpret_cast<const s16x8*>(reinterpret_cast<const char*>(pw) + boff);
        }
#pragma unroll
        for (int s = 0; s < 2; ++s)
#pragma unroll
            for (int f = 0; f < 4; ++f) {
                s16x8 vf = *reinterpret_cast<const s16x8*>(
                    vt + (size_t)(16 * f + lr) * RTOT + kb_g + tt * 64 + s * 32 + lg * 8);
                oacc[f] = __builtin_amdgcn_mfma_f32_16x16x32_bf16(pf[s], vf, oacc[f], 0, 0, 0);
            }
    }

    // store partial O
    float* po = pO + (size_t)slot * 4096;
#pragma unroll
    for (int f = 0; f < 4; ++f)
#pragma unroll
        for (int r = 0; r < 4; ++r) {
            int rit = wid * 16 + lg * 4 + r;
            po[rit * 64 + 16 * f + lr] = oacc[f][r];
        }
}

// ---- merge partials: one wave per output row ----
__global__ __launch_bounds__(256) void k_merge(const float* __restrict__ pm,
                                               const float* __restrict__ pl,
                                               const float* __restrict__ pO,
                                               float* __restrict__ out) {
    int tid = threadIdx.x, w = tid >> 6, h = tid & 63;
    int rglob = blockIdx.x * 4 + w;          // 0..16383
    int b = rglob >> 12, rl = rglob & 4095;
    int qt = rl >> 6, rit = rl & 63;
    int M4 = qt >> 2, rem = qt & 3;
    int nch = M4 + 1;
    int slot0 = b * SLOTS_PER_B + 2 * M4 * (M4 + 1) + rem * (M4 + 1);
    const float KS = 0.1803368801111204f;

    float M = -1e30f;
    for (int cc = 0; cc < nch; ++cc)
        M = fmaxf(M, pm[(size_t)(slot0 + cc) * 64 + rit]);
    float L = 0.f, acc = 0.f;
    for (int cc = 0; cc < nch; ++cc) {
        float ms = pm[(size_t)(slot0 + cc) * 64 + rit];
        float ls = pl[(size_t)(slot0 + cc) * 64 + rit];
        float wgt = exp2f((ms - M) * KS);
        L += ls * wgt;
        acc += pO[(size_t)(slot0 + cc) * 4096 + rit * 64 + h] * wgt;
    }
    out[(size_t)rglob * 64 + h] = acc / L;
}

extern "C" void kernel_launch(void* const* d_in, const int* in_sizes, int n_in,
                              void* d_out, int out_size, void* d_ws, size_t ws_size,
                              hipStream_t stream) {
    const float* q  = (const float*)d_in[0];
    const float* k  = (const float*)d_in[1];
    const float* v  = (const float*)d_in[2];
    const float* wq = (const float*)d_in[3];
    const float* wk = (const float*)d_in[4];
    const float* wv = (const float*)d_in[5];
    // d_in[6] = mask: deterministic causal, not needed
    float* out = (float*)d_out;

    char* ws = (char*)d_ws;
    ushort* qh = (ushort*)(ws);                  // 2 MB   [16384][64] bf16
    ushort* kh = (ushort*)(ws + (2ull << 20));   // 2 MB   [16384][64] bf16
    ushort* vt = (ushort*)(ws + (4ull << 20));   // 2 MB   [64][16384] bf16 (transposed)
    ushort* wt = (ushort*)(ws + (6ull << 20));   // 384 KB [3][64][1024] bf16
    float*  pm = (float*) (ws + (7ull << 20));   // 544 KB [2176][64]
    float*  pl = (float*) (ws + (8ull << 20));   // 544 KB [2176][64]
    float*  pO = (float*) (ws + (9ull << 20));   // 35.7 MB [2176][64][64]

    k_wtrans<<<768, 256, 0, stream>>>(wq, wk, wv, wt);
    k_proj<<<768, 256, 0, stream>>>(q, k, v, wt, qh, kh, vt);
    k_attn_part<<<dim3(16, 64, 4), 256, 0, stream>>>(qh, kh, vt, pm, pl, pO);
    k_merge<<<4096, 256, 0, stream>>>(pm, pl, pO, out);
}